// Round 10
// baseline (134.998 us; speedup 1.0000x reference)
//
#include <hip/hip_runtime.h>
#include <hip/hip_bf16.h>
#include <stdint.h>

// x: [16,128,56,56] f32, w: [256,128,3,3] f32, bias: [256] f32
// out: [16,256,56,56] f32
// Implicit GEMM: M=Cout=256, N=pixels=50176, K = (kh*3+kw, c) = 1152
// Round 17: halve the B-LDS pipe. Across R7-R15 every wave layout kept all
// waves reading the SAME N64 B-columns (4x redundant ds_read_b128): ~576
// cyc/CU per K32-step = ~29 us of R13's 44 -> LDS is the binding pipe.
// This round waves split 2M x 2N: each wave M128 x N32 (acc 8x2), B reads
// per wave-step 4 -> 2 (LDS halved), A-loads 4 -> 8 (L2-resident wt, wave
// pairs share addresses -> L1 dedup). R15's asm ping-pong A-pipeline kept
// (8-wide sets, vmcnt(8)); pre reverted to R15 form. Regs ~158 < 170 (256,3).

typedef __attribute__((ext_vector_type(8))) short short8;
typedef __attribute__((ext_vector_type(4))) float floatx4;

__device__ static inline void gload_lds16(const void* g, void* l) {
  typedef const __attribute__((address_space(1))) unsigned int* gp_t;
  typedef __attribute__((address_space(3))) unsigned int* lp_t;
  __builtin_amdgcn_global_load_lds((gp_t)(uintptr_t)g, (lp_t)(uint32_t)(uintptr_t)l,
                                   16, 0, 0);
}

// ---------- fused pre-pass: NCHW f32 -> padded NHWC bf16 (halo zeroed)
//   + weight f32 -> bf16 in MFMA-frag order wt2[g=m/16][kq][ch][ks][q][r][e]
//   byte strides: r=16, q=256, ks=1024, ch=2048, kq=4096, g=36864 ----------
__global__ __launch_bounds__(256)
void pre_kernel(const float* __restrict__ x, const float* __restrict__ wsrc,
                __hip_bfloat16* __restrict__ xp, __hip_bfloat16* __restrict__ wt) {
  const int b = blockIdx.x;
  if (b < 16 * 58) {
    const int n = b / 58, hp = b % 58;
    __hip_bfloat16* dst = xp + (size_t)(n * 58 + hp) * 58 * 128;
    if (hp == 0 || hp == 57) {
      const uint4 z = {0, 0, 0, 0};
      uint4* p = (uint4*)dst;
      for (int i = threadIdx.x; i < 928; i += 256) p[i] = z;
      return;
    }
    const int h = hp - 1;
    __shared__ float tile[128][57];
    const float* src = x + (size_t)n * (128 * 3136) + h * 56;
    for (int i = threadIdx.x; i < 128 * 14; i += 256) {
      const int c = i / 14, q = i - c * 14;
      const float4 v = ((const float4*)(src + (size_t)c * 3136))[q];
      tile[c][4 * q + 0] = v.x;
      tile[c][4 * q + 1] = v.y;
      tile[c][4 * q + 2] = v.z;
      tile[c][4 * q + 3] = v.w;
    }
    __syncthreads();
    if (threadIdx.x < 32) {
      const uint4 z = {0, 0, 0, 0};
      const int col = (threadIdx.x >> 4) * 57;
      ((uint4*)(dst + (size_t)col * 128))[threadIdx.x & 15] = z;
    }
    __hip_bfloat16* di = dst + 128;
    for (int i = threadIdx.x; i < 56 * 16; i += 256) {
      const int w = i >> 4, c8 = (i & 15) * 8;
      union { uint4 u; __hip_bfloat16 hh[8]; } pk;
#pragma unroll
      for (int j = 0; j < 8; ++j) pk.hh[j] = __float2bfloat16(tile[c8 + j][w]);
      *(uint4*)(di + (size_t)w * 128 + c8) = pk.u;
    }
  } else {
    const int base = (b - 928) * 256 + threadIdx.x;
    for (int t = base; t < 256 * 9 * 128; t += 36 * 256) {
      const int e = t & 7;
      const int rr = (t >> 3) & 15;
      const int q = (t >> 7) & 3;
      const int ks = (t >> 9) & 1;
      const int ch = (t >> 10) & 1;
      const int t11 = t >> 11;
      const int kq = t11 % 9;
      const int g = t11 / 9;
      const int cout = g * 16 + rr;
      const int c = ch * 64 + ks * 32 + q * 8 + e;
      wt[t] = __float2bfloat16(wsrc[(size_t)(cout * 128 + c) * 9 + kq]);
    }
  }
}

// stage one kh-phase (68 rows = 1088 x 16B chunks) into LDS buffer BUF.
// Local row r holds padded row P0 + PH*58 + r; chunk c stored at slot
// c ^ (r&7) (involution pair with the read side; verified R1-R16).
#define STAGE(PH, BUF)                                                        \
  {                                                                           \
    const char* _src = pbase + (PH) * (58 * 256);                             \
    _Pragma("unroll") for (int _i = 0; _i < 4; ++_i) {                        \
      const int _j = _i * 256 + tid;                                          \
      const int _row = _j >> 4;                                               \
      const int _slot = _j & 15;                                              \
      gload_lds16(_src + _row * 256 + ((_slot ^ (_row & 7)) << 4),            \
                  (BUF) + _i * 4096 + wave * 1024);                           \
    }                                                                         \
    if (wave == 0) {                                                          \
      const int _j = 1024 + lane;                                             \
      const int _row = _j >> 4;                                               \
      const int _slot = _j & 15;                                              \
      gload_lds16(_src + _row * 256 + ((_slot ^ (_row & 7)) << 4),            \
                  (BUF) + 16384);                                             \
    }                                                                         \
  }

// asm A-load: 16B per lane, 32-bit voffset off SGPR base (wt).
#define ALOAD(DST, VOFF)                                                      \
  asm volatile("global_load_dwordx4 %0, %1, %2"                               \
               : "=v"(DST) : "v"(VOFF), "s"(wtb64) : "memory")

// one K32 half-step: s = 12*P + T, consumes 8-wide register set SET (parity
// of T), issues A(s+2) back into SET (freed by the MFMAs just issued).
// LASTWAIT: final step of the whole march -> drain (vmcnt(0)).
// SKIP: s+2 > 35 -> no issue (avoid OOB reads past wt).
#define HALF_STEP(SET, T, BUF, LASTWAIT, SKIP)                                \
  {                                                                           \
    const int _t = (T);                                                       \
    const int _kw = _t >> 2;                                                  \
    const int _ksl = _t & 3;                                                  \
    _Pragma("unroll") for (int _nt = 0; _nt < 2; ++_nt) {                     \
      const int _rowL = rbase[_nt] + _kw;                                     \
      const int _pos = (_ksl * 4 + quad) ^ (_rowL & 7);                       \
      bfr[_nt] = *(const short8*)((BUF) + _rowL * 256 + (_pos << 4));         \
    }                                                                         \
    if (LASTWAIT) { asm volatile("s_waitcnt vmcnt(0)" ::: "memory"); }        \
    else          { asm volatile("s_waitcnt vmcnt(8)" ::: "memory"); }        \
    __builtin_amdgcn_sched_barrier(0);                                        \
    _Pragma("unroll") for (int _mt = 0; _mt < 8; ++_mt)                       \
        _Pragma("unroll") for (int _nt = 0; _nt < 2; ++_nt)                   \
            acc[_mt][_nt] = __builtin_amdgcn_mfma_f32_16x16x32_bf16(          \
                SET[_mt], bfr[_nt], acc[_mt][_nt], 0, 0, 0);                  \
    if (!(SKIP)) {                                                            \
      _Pragma("unroll") for (int _mt = 0; _mt < 8; ++_mt) {                   \
        ALOAD(SET[_mt], voff[_mt]);                                           \
        voff[_mt] += 1024;                                                    \
      }                                                                       \
    }                                                                         \
  }

// one kh-phase: 6 rolled double-steps (even step -> aregP, odd -> aregQ).
// LASTP: phase 2 (guard the tail prefetches + final drain).
#define COMPUTE_PH(P, BUF, LASTP)                                             \
  _Pragma("clang loop unroll(disable)") for (int _dd = 0; _dd < 6; ++_dd) {   \
    HALF_STEP(aregP, 2 * _dd, BUF, false, (LASTP) && _dd == 5)                \
    HALF_STEP(aregQ, 2 * _dd + 1, BUF, (LASTP) && _dd == 5,                   \
              (LASTP) && _dd == 5)                                            \
  }

// ---------- main implicit-GEMM MFMA kernel ----------
// 256 thr = 4 waves, wave = (wm = wave>>1, wn = wave&1): each wave owns
// M128 x N32 (acc 8x2). Tile M256 x N64, grid 784. LDS: two kh-phase
// buffers, 68 rows x 256B each = 34816 B. 3 blocks/CU.
// A offsets LINEAR in step s: voff[mt] = (wm*8+mt)*36864 + lane*16 + s*1024.
__global__ __launch_bounds__(256, 3)
void conv_gemm_kernel(const __hip_bfloat16* __restrict__ xp,
                      const __hip_bfloat16* __restrict__ wt,
                      const float* __restrict__ bias,
                      float* __restrict__ out) {
  __shared__ __align__(16) char smem[2][17408];

  const int tid = threadIdx.x;
  const int lane = tid & 63;
  const int wave = tid >> 6;
  const int wm = wave >> 1;
  const int wn = wave & 1;
  const int col = lane & 15;
  const int quad = lane >> 4;

  // XCD-contiguous tiles: 784 = 8 XCD x 98 n-tiles (bijective: 784 % 8 == 0)
  const int id = blockIdx.x;
  const int xcd = id & 7;
  const int nt_ = xcd * 98 + (id >> 3);
  const int n0 = nt_ * 64;  // 64 consecutive pixels; never crosses an image

  // patch base: padded-pixel index of pixel n0 at tap (0,0)
  const int nimg0 = n0 / 3136;
  const int rem0 = n0 - nimg0 * 3136;
  const int hh0 = rem0 / 56;
  const int ww0 = rem0 - hh0 * 56;
  const int P0 = (nimg0 * 58 + hh0) * 58 + ww0;
  const char* pbase = (const char*)xp + (size_t)P0 * 256;

  STAGE(0, smem[0]);  // phase-0 patch in flight

  const uint64_t wtb64 = (uint64_t)(uintptr_t)wt;

  // voff[mt] = offset of the NEXT A-frag to issue for sub-panel mt
  uint32_t voff[8];
#pragma unroll
  for (int mt = 0; mt < 8; ++mt)
    voff[mt] = (uint32_t)((wm * 8 + mt) * 36864 + lane * 16);

  short8 aregP[8], aregQ[8], bfr[2];

  // prologue: issue A(0) -> P, A(1) -> Q (they drain at the barrier below)
#pragma unroll
  for (int mt = 0; mt < 8; ++mt) { ALOAD(aregP[mt], voff[mt]); voff[mt] += 1024; }
#pragma unroll
  for (int mt = 0; mt < 8; ++mt) { ALOAD(aregQ[mt], voff[mt]); voff[mt] += 1024; }

  // ---- per-lane patch row bases (tap (0,0)); tiles never cross images ----
  int rbase[2];
#pragma unroll
  for (int nt = 0; nt < 2; ++nt) {
    const int pix = n0 + wn * 32 + nt * 16 + col;
    const int ni = pix / 3136;
    const int re = pix - ni * 3136;
    const int ph = re / 56;
    const int pw = re - ph * 56;
    rbase[nt] = (ni * 58 + ph) * 58 + pw - P0;
  }

  floatx4 acc[8][2];
#pragma unroll
  for (int a = 0; a < 8; ++a)
#pragma unroll
    for (int c = 0; c < 2; ++c) acc[a][c] = (floatx4)0.f;

  __syncthreads();      // phase-0 patch + A(0)/A(1) ready (barrier drains)
  STAGE(1, smem[1]);    // async: phase-1 staged during phase-0 compute
  COMPUTE_PH(0, smem[0], false);
  __syncthreads();      // phase-1 ready; all waves done reading buf0
  STAGE(2, smem[0]);    // async: phase-2 staged during phase-1 compute
  COMPUTE_PH(1, smem[1], false);
  __syncthreads();      // phase-2 ready
  COMPUTE_PH(2, smem[0], true);

  // ---- epilogue: bias + store (C/D: row m=quad*4+rr, col n=lane&15) ----
  const int rb = quad * 4;
#pragma unroll
  for (int nt = 0; nt < 2; ++nt) {
    const int pix = n0 + wn * 32 + nt * 16 + col;
    const int nimg = pix / 3136;
    const int rem = pix - nimg * 3136;
    float* op = out + (size_t)nimg * (256 * 3136) + rem;
#pragma unroll
    for (int mt = 0; mt < 8; ++mt) {
      const int mb = wm * 128 + mt * 16 + rb;
#pragma unroll
      for (int rr = 0; rr < 4; ++rr) {
        op[(size_t)(mb + rr) * 3136] = acc[mt][nt][rr] + bias[mb + rr];
      }
    }
  }
}

// ---------- fallback: direct fp32 conv (only if ws too small) ----------
__global__ __launch_bounds__(256)
void direct_conv_kernel(const float* __restrict__ x, const float* __restrict__ wgt,
                        const float* __restrict__ bias, float* __restrict__ out) {
  const long t = (long)blockIdx.x * 256 + threadIdx.x;
  if (t >= 16L * 256 * 3136) return;
  const int w = t % 56;
  const int h = (t / 56) % 56;
  const int o = (t / 3136) % 256;
  const int n = t / (256L * 3136);
  float s = bias[o];
  for (int c = 0; c < 128; ++c)
    for (int kh = 0; kh < 3; ++kh) {
      const int hh = h + kh - 1;
      if (hh < 0 || hh >= 56) continue;
      for (int kw = 0; kw < 3; ++kw) {
        const int ww = w + kw - 1;
        if (ww < 0 || ww >= 56) continue;
        s += x[((size_t)(n * 128 + c) * 56 + hh) * 56 + ww] *
             wgt[((size_t)(o * 128 + c) * 3 + kh) * 3 + kw];
      }
    }
  out[t] = s;
}

extern "C" void kernel_launch(void* const* d_in, const int* in_sizes, int n_in,
                              void* d_out, int out_size, void* d_ws, size_t ws_size,
                              hipStream_t stream) {
  const float* x = (const float*)d_in[0];
  const float* w = (const float*)d_in[1];
  const float* b = (const float*)d_in[2];
  float* out = (float*)d_out;

  const size_t xp_bytes = (size_t)16 * 58 * 58 * 128 * 2;  // 13,778,944
  const size_t wt_bytes = (size_t)256 * 9 * 128 * 2;       //    589,824
  // Staging bounds: worst tile P0=53640, phase-2 last byte = (P0 + 2*58 + 68)
  // * 256 = 13,778,944 = exactly xp end. A-prefetch guarded (no read past wt;
  // max voff = 15*36864 + 1008 + 35*1024 + 16 = 589,824 = exactly wt end).

  if (ws_size >= xp_bytes + wt_bytes) {
    __hip_bfloat16* xp = (__hip_bfloat16*)d_ws;
    __hip_bfloat16* wt = (__hip_bfloat16*)((char*)d_ws + xp_bytes);
    hipLaunchKernelGGL(pre_kernel, dim3(16 * 58 + 36), dim3(256), 0, stream,
                       x, w, xp, wt);
    hipLaunchKernelGGL(conv_gemm_kernel, dim3(784), dim3(256), 0, stream,
                       xp, wt, b, out);
  } else {
    const long total = 16L * 256 * 3136;
    hipLaunchKernelGGL(direct_conv_kernel, dim3((unsigned)((total + 255) / 256)),
                       dim3(256), 0, stream, x, w, b, out);
  }
}

// Round 12
// 124.253 us; speedup vs baseline: 1.0865x; 1.0865x over previous
//
#include <hip/hip_runtime.h>
#include <hip/hip_bf16.h>
#include <stdint.h>

// x: [16,128,56,56] f32, w: [256,128,3,3] f32, bias: [256] f32
// out: [16,256,56,56] f32
// Implicit GEMM: M=Cout=256, N=pixels=50176, K = (kh*3+kw, c) = 1152
// Round 19: dist-3 asm A-ring, BRANCHLESS. R18 (same theory) died in a
// SIGABRT with no counters -- suspected toolchain ICE on the runtime-branched
// counted-wait macro. This version: phases 0/1 = rolled 2x6 loops where every
// half-step is identical (vmcnt(8) + issue, no branches); phase 2 = fully
// straight-line 12 half-steps with LITERAL waits (8x9, then 8,4,0) and
// literal issue flags. Sets S0/S1/S2 rotate; 12 steps/phase = 0 mod 3 keeps
// phase starts on S0. A-ring cover ~3 half-steps ~230 cyc >= L2 latency
// 200-225 (m125/126). All addresses identical to R15/R18 (verified in-bounds).

typedef __attribute__((ext_vector_type(8))) short short8;
typedef __attribute__((ext_vector_type(4))) float floatx4;

__device__ static inline void gload_lds16(const void* g, void* l) {
  typedef const __attribute__((address_space(1))) unsigned int* gp_t;
  typedef __attribute__((address_space(3))) unsigned int* lp_t;
  __builtin_amdgcn_global_load_lds((gp_t)(uintptr_t)g, (lp_t)(uint32_t)(uintptr_t)l,
                                   16, 0, 0);
}

// ---------- fused pre-pass: NCHW f32 -> padded NHWC bf16 (halo zeroed)
//   + weight f32 -> bf16 in MFMA-frag order wt2[g=m/16][kq][ch][ks][q][r][e]
//   byte strides: r=16, q=256, ks=1024, ch=2048, kq=4096, g=36864 ----------
__global__ __launch_bounds__(256)
void pre_kernel(const float* __restrict__ x, const float* __restrict__ wsrc,
                __hip_bfloat16* __restrict__ xp, __hip_bfloat16* __restrict__ wt) {
  const int b = blockIdx.x;
  if (b < 16 * 58) {
    const int n = b / 58, hp = b % 58;
    __hip_bfloat16* dst = xp + (size_t)(n * 58 + hp) * 58 * 128;
    if (hp == 0 || hp == 57) {
      const uint4 z = {0, 0, 0, 0};
      uint4* p = (uint4*)dst;
      for (int i = threadIdx.x; i < 928; i += 256) p[i] = z;
      return;
    }
    const int h = hp - 1;
    __shared__ float tile[128][57];
    const float* src = x + (size_t)n * (128 * 3136) + h * 56;
    for (int i = threadIdx.x; i < 128 * 14; i += 256) {
      const int c = i / 14, q = i - c * 14;
      const float4 v = ((const float4*)(src + (size_t)c * 3136))[q];
      tile[c][4 * q + 0] = v.x;
      tile[c][4 * q + 1] = v.y;
      tile[c][4 * q + 2] = v.z;
      tile[c][4 * q + 3] = v.w;
    }
    __syncthreads();
    if (threadIdx.x < 32) {
      const uint4 z = {0, 0, 0, 0};
      const int col = (threadIdx.x >> 4) * 57;
      ((uint4*)(dst + (size_t)col * 128))[threadIdx.x & 15] = z;
    }
    __hip_bfloat16* di = dst + 128;
    for (int i = threadIdx.x; i < 56 * 16; i += 256) {
      const int w = i >> 4, c8 = (i & 15) * 8;
      union { uint4 u; __hip_bfloat16 hh[8]; } pk;
#pragma unroll
      for (int j = 0; j < 8; ++j) pk.hh[j] = __float2bfloat16(tile[c8 + j][w]);
      *(uint4*)(di + (size_t)w * 128 + c8) = pk.u;
    }
  } else {
    const int base = (b - 928) * 256 + threadIdx.x;
    for (int t = base; t < 256 * 9 * 128; t += 36 * 256) {
      const int e = t & 7;
      const int rr = (t >> 3) & 15;
      const int q = (t >> 7) & 3;
      const int ks = (t >> 9) & 1;
      const int ch = (t >> 10) & 1;
      const int t11 = t >> 11;
      const int kq = t11 % 9;
      const int g = t11 / 9;
      const int cout = g * 16 + rr;
      const int c = ch * 64 + ks * 32 + q * 8 + e;
      wt[t] = __float2bfloat16(wsrc[(size_t)(cout * 128 + c) * 9 + kq]);
    }
  }
}

// stage one kh-phase (68 rows = 1088 x 16B chunks) into LDS buffer BUF.
// Local row r holds padded row P0 + PH*58 + r; chunk c stored at slot
// c ^ (r&7) (involution pair with the read side; verified R1-R17).
#define STAGE(PH, BUF)                                                        \
  {                                                                           \
    const char* _src = pbase + (PH) * (58 * 256);                             \
    _Pragma("unroll") for (int _i = 0; _i < 4; ++_i) {                        \
      const int _j = _i * 256 + tid;                                          \
      const int _row = _j >> 4;                                               \
      const int _slot = _j & 15;                                              \
      gload_lds16(_src + _row * 256 + ((_slot ^ (_row & 7)) << 4),            \
                  (BUF) + _i * 4096 + wave * 1024);                           \
    }                                                                         \
    if (wave == 0) {                                                          \
      const int _j = 1024 + lane;                                             \
      const int _row = _j >> 4;                                               \
      const int _slot = _j & 15;                                              \
      gload_lds16(_src + _row * 256 + ((_slot ^ (_row & 7)) << 4),            \
                  (BUF) + 16384);                                             \
    }                                                                         \
  }

// asm A-load: 16B per lane, 32-bit voffset off SGPR base (wt).
#define ALOAD(DST, VOFF)                                                      \
  asm volatile("global_load_dwordx4 %0, %1, %2"                               \
               : "=v"(DST) : "v"(VOFF), "s"(wtb64) : "memory")

// one K32 half-step, BRANCHLESS: literal WAITN (stringized), literal DOISSUE.
// Consumes SET (holds A of this step); issues A(step+3) back into SET.
#define HS(SET, LT, WAITN, DOISSUE, BUF)                                      \
  {                                                                           \
    const int _t = (LT);                                                      \
    const int _kw = _t >> 2;                                                  \
    const int _ksl = _t & 3;                                                  \
    _Pragma("unroll") for (int _nt = 0; _nt < 4; ++_nt) {                     \
      const int _rowL = rbase[_nt] + _kw;                                     \
      const int _pos = (_ksl * 4 + quad) ^ (_rowL & 7);                       \
      bfr[_nt] = *(const short8*)((BUF) + _rowL * 256 + (_pos << 4));         \
    }                                                                         \
    asm volatile("s_waitcnt vmcnt(" #WAITN ")" ::: "memory");                 \
    __builtin_amdgcn_sched_barrier(0);                                        \
    _Pragma("unroll") for (int _mt = 0; _mt < 4; ++_mt)                       \
        _Pragma("unroll") for (int _nt = 0; _nt < 4; ++_nt)                   \
            acc[_mt][_nt] = __builtin_amdgcn_mfma_f32_16x16x32_bf16(          \
                SET[_mt], bfr[_nt], acc[_mt][_nt], 0, 0, 0);                  \
    if (DOISSUE) {                                                            \
      _Pragma("unroll") for (int _mt = 0; _mt < 4; ++_mt) {                   \
        ALOAD(SET[_mt], voff[_mt]);                                           \
        voff[_mt] += 1024;                                                    \
      }                                                                       \
    }                                                                         \
  }

// phases 0/1: rolled 2 x 6 half-steps, all identical (wait 8, always issue)
#define COMPUTE_MAIN(BUF)                                                     \
  _Pragma("clang loop unroll(disable)") for (int _u = 0; _u < 2; ++_u) {      \
    HS(aregS0, 6 * _u + 0, 8, 1, BUF)                                         \
    HS(aregS1, 6 * _u + 1, 8, 1, BUF)                                         \
    HS(aregS2, 6 * _u + 2, 8, 1, BUF)                                         \
    HS(aregS0, 6 * _u + 3, 8, 1, BUF)                                         \
    HS(aregS1, 6 * _u + 4, 8, 1, BUF)                                         \
    HS(aregS2, 6 * _u + 5, 8, 1, BUF)                                         \
  }

// phase 2: straight-line, literal waits/issues. Global steps 24..35:
// locals 0..8 issue A(27)..A(35); locals 9/10/11 wait 8/4/0, no issue.
#define COMPUTE_TAIL(BUF)                                                     \
  HS(aregS0, 0, 8, 1, BUF)                                                    \
  HS(aregS1, 1, 8, 1, BUF)                                                    \
  HS(aregS2, 2, 8, 1, BUF)                                                    \
  HS(aregS0, 3, 8, 1, BUF)                                                    \
  HS(aregS1, 4, 8, 1, BUF)                                                    \
  HS(aregS2, 5, 8, 1, BUF)                                                    \
  HS(aregS0, 6, 8, 1, BUF)                                                    \
  HS(aregS1, 7, 8, 1, BUF)                                                    \
  HS(aregS2, 8, 8, 1, BUF)                                                    \
  HS(aregS0, 9, 8, 0, BUF)                                                    \
  HS(aregS1, 10, 4, 0, BUF)                                                   \
  HS(aregS2, 11, 0, 0, BUF)

// ---------- main implicit-GEMM MFMA kernel ----------
// 256 thr = 4 waves, each wave M64 x N64 (acc 4x4). Tile M256 x N64, grid 784.
// LDS: two kh-phase buffers, 68 rows x 256B each = 34816 B. 3 blocks/CU.
// A offsets LINEAR in step s: voff[mt] = (wave*4+mt)*36864 + lane*16 + s*1024.
__global__ __launch_bounds__(256, 3)
void conv_gemm_kernel(const __hip_bfloat16* __restrict__ xp,
                      const __hip_bfloat16* __restrict__ wt,
                      const float* __restrict__ bias,
                      float* __restrict__ out) {
  __shared__ __align__(16) char smem[2][17408];

  const int tid = threadIdx.x;
  const int lane = tid & 63;
  const int wave = tid >> 6;
  const int col = lane & 15;
  const int quad = lane >> 4;

  // XCD-contiguous tiles: 784 = 8 XCD x 98 n-tiles (bijective: 784 % 8 == 0)
  const int id = blockIdx.x;
  const int xcd = id & 7;
  const int nt_ = xcd * 98 + (id >> 3);
  const int n0 = nt_ * 64;  // 64 consecutive pixels; never crosses an image

  // patch base: padded-pixel index of pixel n0 at tap (0,0)
  const int nimg0 = n0 / 3136;
  const int rem0 = n0 - nimg0 * 3136;
  const int hh0 = rem0 / 56;
  const int ww0 = rem0 - hh0 * 56;
  const int P0 = (nimg0 * 58 + hh0) * 58 + ww0;
  const char* pbase = (const char*)xp + (size_t)P0 * 256;

  STAGE(0, smem[0]);  // phase-0 patch in flight

  const uint64_t wtb64 = (uint64_t)(uintptr_t)wt;

  // voff[mt] = offset of the NEXT A-frag to issue for sub-panel mt
  uint32_t voff[4];
#pragma unroll
  for (int mt = 0; mt < 4; ++mt)
    voff[mt] = (uint32_t)((wave * 4 + mt) * 36864 + lane * 16);

  short8 aregS0[4], aregS1[4], aregS2[4], bfr[4];

  // prologue: issue A(0)->S0, A(1)->S1, A(2)->S2 (drain at barrier below)
#pragma unroll
  for (int mt = 0; mt < 4; ++mt) { ALOAD(aregS0[mt], voff[mt]); voff[mt] += 1024; }
#pragma unroll
  for (int mt = 0; mt < 4; ++mt) { ALOAD(aregS1[mt], voff[mt]); voff[mt] += 1024; }
#pragma unroll
  for (int mt = 0; mt < 4; ++mt) { ALOAD(aregS2[mt], voff[mt]); voff[mt] += 1024; }

  // ---- per-lane patch row bases (tap (0,0)); tiles never cross images ----
  int rbase[4];
#pragma unroll
  for (int nt = 0; nt < 4; ++nt) {
    const int pix = n0 + nt * 16 + col;
    const int ni = pix / 3136;
    const int re = pix - ni * 3136;
    const int ph = re / 56;
    const int pw = re - ph * 56;
    rbase[nt] = (ni * 58 + ph) * 58 + pw - P0;
  }

  floatx4 acc[4][4];
#pragma unroll
  for (int a = 0; a < 4; ++a)
#pragma unroll
    for (int c = 0; c < 4; ++c) acc[a][c] = (floatx4)0.f;

  __syncthreads();      // phase-0 patch + A(0..2) ready (barrier drains vmcnt)
  STAGE(1, smem[1]);    // async: phase-1 staged during phase-0 compute
  COMPUTE_MAIN(smem[0]);
  __syncthreads();      // phase-1 ready; all waves done reading buf0
  STAGE(2, smem[0]);    // async: phase-2 staged during phase-1 compute
  COMPUTE_MAIN(smem[1]);
  __syncthreads();      // phase-2 ready
  COMPUTE_TAIL(smem[0]);

  // ---- epilogue: bias + store (C/D: row m=quad*4+rr, col n=lane&15) ----
  const int rb = quad * 4;
#pragma unroll
  for (int nt = 0; nt < 4; ++nt) {
    const int pix = n0 + nt * 16 + col;
    const int nimg = pix / 3136;
    const int rem = pix - nimg * 3136;
    float* op = out + (size_t)nimg * (256 * 3136) + rem;
#pragma unroll
    for (int mt = 0; mt < 4; ++mt) {
      const int mb = wave * 64 + mt * 16 + rb;
#pragma unroll
      for (int rr = 0; rr < 4; ++rr) {
        op[(size_t)(mb + rr) * 3136] = acc[mt][nt][rr] + bias[mb + rr];
      }
    }
  }
}

// ---------- fallback: direct fp32 conv (only if ws too small) ----------
__global__ __launch_bounds__(256)
void direct_conv_kernel(const float* __restrict__ x, const float* __restrict__ wgt,
                        const float* __restrict__ bias, float* __restrict__ out) {
  const long t = (long)blockIdx.x * 256 + threadIdx.x;
  if (t >= 16L * 256 * 3136) return;
  const int w = t % 56;
  const int h = (t / 56) % 56;
  const int o = (t / 3136) % 256;
  const int n = t / (256L * 3136);
  float s = bias[o];
  for (int c = 0; c < 128; ++c)
    for (int kh = 0; kh < 3; ++kh) {
      const int hh = h + kh - 1;
      if (hh < 0 || hh >= 56) continue;
      for (int kw = 0; kw < 3; ++kw) {
        const int ww = w + kw - 1;
        if (ww < 0 || ww >= 56) continue;
        s += x[((size_t)(n * 128 + c) * 56 + hh) * 56 + ww] *
             wgt[((size_t)(o * 128 + c) * 3 + kh) * 3 + kw];
      }
    }
  out[t] = s;
}

extern "C" void kernel_launch(void* const* d_in, const int* in_sizes, int n_in,
                              void* d_out, int out_size, void* d_ws, size_t ws_size,
                              hipStream_t stream) {
  const float* x = (const float*)d_in[0];
  const float* w = (const float*)d_in[1];
  const float* b = (const float*)d_in[2];
  float* out = (float*)d_out;

  const size_t xp_bytes = (size_t)16 * 58 * 58 * 128 * 2;  // 13,778,944
  const size_t wt_bytes = (size_t)256 * 9 * 128 * 2;       //    589,824
  // Staging bounds: worst tile P0=53640, phase-2 last byte = (P0 + 2*58 + 68)
  // * 256 = 13,778,944 = exactly xp end. A-issues stop at A(35); max voff
  // touches byte 589,824 = exactly wt end. Fully in-bounds.

  if (ws_size >= xp_bytes + wt_bytes) {
    __hip_bfloat16* xp = (__hip_bfloat16*)d_ws;
    __hip_bfloat16* wt = (__hip_bfloat16*)((char*)d_ws + xp_bytes);
    hipLaunchKernelGGL(pre_kernel, dim3(16 * 58 + 36), dim3(256), 0, stream,
                       x, w, xp, wt);
    hipLaunchKernelGGL(conv_gemm_kernel, dim3(784), dim3(256), 0, stream,
                       xp, wt, b, out);
  } else {
    const long total = 16L * 256 * 3136;
    hipLaunchKernelGGL(direct_conv_kernel, dim3((unsigned)((total + 255) / 256)),
                       dim3(256), 0, stream, x, w, b, out);
  }
}